// Round 2
// baseline (468.704 us; speedup 1.0000x reference)
//
#include <hip/hip_runtime.h>
#include <hip/hip_bf16.h>

typedef __bf16 bf16;
typedef __attribute__((ext_vector_type(8))) __bf16 bf16x8;
typedef __attribute__((ext_vector_type(4))) float f32x4;

#define MFMA_BF16(a, b, c) __builtin_amdgcn_mfma_f32_16x16x32_bf16((a), (b), (c), 0, 0, 0)

__device__ __forceinline__ void gload_lds16(const bf16* g, bf16* l) {
  __builtin_amdgcn_global_load_lds(
      (__attribute__((address_space(1))) void*)(g),
      (__attribute__((address_space(3))) void*)(l), 16, 0, 0);
}

// ------- transpose + f32->bf16 convert of both weight matrices (1024x1024) ----
__global__ void transcvt2(const float* __restrict__ W0, bf16* __restrict__ T0,
                          const float* __restrict__ W1, bf16* __restrict__ T1) {
  const float* src = blockIdx.z ? W1 : W0;
  bf16* dst = blockIdx.z ? T1 : T0;
  __shared__ float t[32][33];
  const int bx = blockIdx.x * 32, by = blockIdx.y * 32;
  const int tx = threadIdx.x, ty = threadIdx.y;
#pragma unroll
  for (int i = 0; i < 4; ++i)
    t[ty + i * 8][tx] = src[(long)(by + ty + i * 8) * 1024 + bx + tx];
  __syncthreads();
#pragma unroll
  for (int i = 0; i < 4; ++i)
    dst[(long)(bx + ty + i * 8) * 1024 + by + tx] = (bf16)t[tx][ty + i * 8];
}

// ------- GEMM: C[M,1024] = A[M,1024] @ Bt[1024,1024]^T + bias -----------------
// Bt is [n][k] row-major bf16 (i.e. W^T). 128x128 tile, BK=32, 4 waves.
// A_IS_F32: A is f32, reg-staged + converted. OUT_F32: C stored as f32.
template <bool A_IS_F32, bool OUT_F32>
__global__ __launch_bounds__(256) void gemm_bt(const void* __restrict__ Av,
                                               const bf16* __restrict__ Bt,
                                               const float* __restrict__ bias,
                                               void* __restrict__ Cv) {
  __shared__ __align__(16) bf16 As[128 * 32];
  __shared__ __align__(16) bf16 Bs[128 * 32];
  const int tid = threadIdx.x;
  const int l = tid & 63, w = tid >> 6;
  const int wr = w >> 1, wc = w & 1;
  const int lo = l & 15, g = l >> 4;
  const int m0 = blockIdx.x * 128;
  const int n0 = blockIdx.y * 128;
  const bf16* Ab = (const bf16*)Av + (long)m0 * 1024;
  const float* Af = (const float*)Av + (long)m0 * 1024;
  const bf16* Bb = Bt + (long)n0 * 1024;
  const int srow = tid >> 2;          // 0..63
  const int schunk = (tid & 3) * 8;   // k element offset of 16B chunk
  f32x4 acc[4][4] = {};
  for (int k0 = 0; k0 < 1024; k0 += 32) {
    __syncthreads();
    if constexpr (A_IS_F32) {
#pragma unroll
      for (int h = 0; h < 2; ++h) {
        const float* p = Af + (long)(srow + h * 64) * 1024 + k0 + schunk;
        f32x4 u0 = *(const f32x4*)p;
        f32x4 u1 = *(const f32x4*)(p + 4);
        bf16x8 vv;
#pragma unroll
        for (int e = 0; e < 4; ++e) {
          vv[e] = (bf16)u0[e];
          vv[4 + e] = (bf16)u1[e];
        }
        *(bf16x8*)&As[h * 2048 + tid * 8] = vv;
      }
    } else {
      gload_lds16(Ab + (long)srow * 1024 + k0 + schunk, As + tid * 8);
      gload_lds16(Ab + (long)(srow + 64) * 1024 + k0 + schunk, As + 2048 + tid * 8);
    }
    gload_lds16(Bb + (long)srow * 1024 + k0 + schunk, Bs + tid * 8);
    gload_lds16(Bb + (long)(srow + 64) * 1024 + k0 + schunk, Bs + 2048 + tid * 8);
    __syncthreads();   // drains vmcnt/lgkm: staging complete
    bf16x8 af[4], bfr[4];
#pragma unroll
    for (int m = 0; m < 4; ++m)
      af[m] = *(const bf16x8*)&As[(wr * 64 + m * 16 + lo) * 32 + g * 8];
#pragma unroll
    for (int n = 0; n < 4; ++n)
      bfr[n] = *(const bf16x8*)&Bs[(wc * 64 + n * 16 + lo) * 32 + g * 8];
#pragma unroll
    for (int m = 0; m < 4; ++m)
#pragma unroll
      for (int n = 0; n < 4; ++n)
        acc[m][n] = MFMA_BF16(af[m], bfr[n], acc[m][n]);
  }
#pragma unroll
  for (int n = 0; n < 4; ++n) {
    const int col = n0 + wc * 64 + n * 16 + lo;
    const float bv = bias[col];
#pragma unroll
    for (int m = 0; m < 4; ++m) {
      const long row0 = m0 + wr * 64 + m * 16 + g * 4;
#pragma unroll
      for (int j = 0; j < 4; ++j) {
        if constexpr (OUT_F32)
          ((float*)Cv)[(row0 + j) * 1024 + col] = acc[m][n][j] + bv;
        else
          ((bf16*)Cv)[(row0 + j) * 1024 + col] = (bf16)(acc[m][n][j] + bv);
      }
    }
  }
}

// ---------------- flash attention, Q=K=V = proj head panel [2048,64] ----------
// grid: B*H*16 blocks; block: 4 waves, each wave owns 32 q-rows (QB=128).
// KV tile = 64. K frags read from global (L2/L3-resident). V staged transposed.
__global__ __launch_bounds__(256) void attn(const bf16* __restrict__ proj,
                                            bf16* __restrict__ merged) {
  __shared__ __align__(16) bf16 Vt[64][72];        // [d][kv], +8 pad
  __shared__ __align__(16) bf16 Plds[4][32][72];   // per-wave P, +8 pad
  const int bid = blockIdx.x;
  const int qb = bid & 15;
  const int h = (bid >> 4) & 15;
  const int b = bid >> 8;
  const bf16* P = proj + (long)b * 2097152 + (long)h * 131072;  // [2048][64]
  const int tid = threadIdx.x;
  const int w = tid >> 6, l = tid & 63;
  const int lo = l & 15, g = l >> 4;
  const int qrow = qb * 128 + w * 32;

  // Q fragments, pre-scaled by 1/sqrt(dk)=0.125 (exact in bf16: pow2)
  bf16x8 qa[2][2];
#pragma unroll
  for (int m = 0; m < 2; ++m)
#pragma unroll
    for (int ks = 0; ks < 2; ++ks) {
      bf16x8 t = *(const bf16x8*)&P[(qrow + m * 16 + lo) * 64 + ks * 32 + g * 8];
#pragma unroll
      for (int e = 0; e < 8; ++e) t[e] = (bf16)((float)t[e] * 0.125f);
      qa[m][ks] = t;
    }

  f32x4 o[2][4] = {};
  float mrow[2][4], lrow[2][4];
#pragma unroll
  for (int m = 0; m < 2; ++m)
#pragma unroll
    for (int j = 0; j < 4; ++j) { mrow[m][j] = -1e30f; lrow[m][j] = 0.f; }

  const int skv = tid >> 3;  // 0..31
  const int sc = tid & 7;    // chunk 0..7

  for (int kv0 = 0; kv0 < 2048; kv0 += 64) {
    __syncthreads();  // all waves done reading previous Vt
    // stage V^T: Vt[d][kv] = V[kv0+kv][d]
#pragma unroll
    for (int it = 0; it < 2; ++it) {
      const int kv = skv + it * 32;
      bf16x8 v = *(const bf16x8*)&P[(long)(kv0 + kv) * 64 + sc * 8];
#pragma unroll
      for (int e = 0; e < 8; ++e) Vt[sc * 8 + e][kv] = v[e];
    }
    __syncthreads();

    // S = (Q*0.125) K^T   — K fragment straight from global
    f32x4 s[2][4] = {};
#pragma unroll
    for (int n = 0; n < 4; ++n)
#pragma unroll
      for (int ks = 0; ks < 2; ++ks) {
        bf16x8 kb = *(const bf16x8*)&P[(long)(kv0 + n * 16 + lo) * 64 + ks * 32 + g * 8];
        s[0][n] = MFMA_BF16(qa[0][ks], kb, s[0][n]);
        s[1][n] = MFMA_BF16(qa[1][ks], kb, s[1][n]);
      }

    // online softmax: lane group g owns rows m*16 + g*4 + j
#pragma unroll
    for (int m = 0; m < 2; ++m)
#pragma unroll
      for (int j = 0; j < 4; ++j) {
        float mx = fmaxf(fmaxf(s[m][0][j], s[m][1][j]),
                         fmaxf(s[m][2][j], s[m][3][j]));
#pragma unroll
        for (int d = 1; d < 16; d <<= 1) mx = fmaxf(mx, __shfl_xor(mx, d));
        const float mnew = fmaxf(mrow[m][j], mx);
        const float corr = __expf(mrow[m][j] - mnew);
        mrow[m][j] = mnew;
        float psum = 0.f;
#pragma unroll
        for (int n = 0; n < 4; ++n) {
          const float p = __expf(s[m][n][j] - mnew);
          psum += p;
          Plds[w][m * 16 + g * 4 + j][n * 16 + lo] = (bf16)p;
        }
#pragma unroll
        for (int d = 1; d < 16; d <<= 1) psum += __shfl_xor(psum, d);
        lrow[m][j] = lrow[m][j] * corr + psum;
#pragma unroll
        for (int n = 0; n < 4; ++n) o[m][n][j] *= corr;
      }

    // O += P V  (A from Plds, B from Vt)
#pragma unroll
    for (int ks = 0; ks < 2; ++ks) {
      bf16x8 pa0 = *(const bf16x8*)&Plds[w][lo][ks * 32 + g * 8];
      bf16x8 pa1 = *(const bf16x8*)&Plds[w][16 + lo][ks * 32 + g * 8];
#pragma unroll
      for (int n = 0; n < 4; ++n) {
        bf16x8 vb = *(const bf16x8*)&Vt[n * 16 + lo][ks * 32 + g * 8];
        o[0][n] = MFMA_BF16(pa0, vb, o[0][n]);
        o[1][n] = MFMA_BF16(pa1, vb, o[1][n]);
      }
    }
  }

  // finalize + store into merged layout: merged[b][sq][h*64 + d]
  bf16* mb = merged + (long)b * 2097152 + h * 64;
#pragma unroll
  for (int m = 0; m < 2; ++m)
#pragma unroll
    for (int j = 0; j < 4; ++j) {
      const float inv = 1.0f / lrow[m][j];
      const int sq = qrow + m * 16 + g * 4 + j;
#pragma unroll
      for (int n = 0; n < 4; ++n)
        mb[(long)sq * 1024 + n * 16 + lo] = (bf16)(o[m][n][j] * inv);
    }
}

extern "C" void kernel_launch(void* const* d_in, const int* in_sizes, int n_in,
                              void* d_out, int out_size, void* d_ws, size_t ws_size,
                              hipStream_t stream) {
  const float* x = (const float*)d_in[0];
  const float* Wqkv = (const float*)d_in[1];
  const float* bqkv = (const float*)d_in[2];
  const float* Wo = (const float*)d_in[3];
  const float* bo = (const float*)d_in[4];
  float* out = (float*)d_out;

  char* ws = (char*)d_ws;
  bf16* proj = (bf16*)(ws);                     // 16.78 MB  [4][2048][1024]
  bf16* merged = (bf16*)(ws + 16777216);        // 16.78 MB  [4][2048][1024]
  bf16* WqkvT = (bf16*)(ws + 33554432);         // 2 MB      [n][k]
  bf16* WoT = (bf16*)(ws + 35651584);           // 2 MB      [n][k]

  transcvt2<<<dim3(32, 32, 2), dim3(32, 8), 0, stream>>>(Wqkv, WqkvT, Wo, WoT);
  gemm_bt<true, false><<<dim3(64, 8), dim3(256), 0, stream>>>(x, WqkvT, bqkv, proj);
  attn<<<dim3(1024), dim3(256), 0, stream>>>(proj, merged);
  gemm_bt<false, true><<<dim3(64, 8), dim3(256), 0, stream>>>(merged, WoT, bo, out);
}

// Round 5
// 343.777 us; speedup vs baseline: 1.3634x; 1.3634x over previous
//
#include <hip/hip_runtime.h>
#include <hip/hip_bf16.h>

typedef __bf16 bf16;
typedef __attribute__((ext_vector_type(8))) __bf16 bf16x8;
typedef __attribute__((ext_vector_type(4))) float f32x4;

#define MFMA_BF16(a, b, c) __builtin_amdgcn_mfma_f32_16x16x32_bf16((a), (b), (c), 0, 0, 0)
#define EXP2F(x) __builtin_amdgcn_exp2f(x)

__device__ __forceinline__ void gload_lds16(const bf16* g, bf16* l) {
  __builtin_amdgcn_global_load_lds(
      (__attribute__((address_space(1))) void*)(g),
      (__attribute__((address_space(3))) void*)(l), 16, 0, 0);
}

// ------- transpose + f32->bf16 convert of both weight matrices (1024x1024) ----
__global__ void transcvt2(const float* __restrict__ W0, bf16* __restrict__ T0,
                          const float* __restrict__ W1, bf16* __restrict__ T1) {
  const float* src = blockIdx.z ? W1 : W0;
  bf16* dst = blockIdx.z ? T1 : T0;
  __shared__ float t[32][33];
  const int bx = blockIdx.x * 32, by = blockIdx.y * 32;
  const int tx = threadIdx.x, ty = threadIdx.y;
#pragma unroll
  for (int i = 0; i < 4; ++i)
    t[ty + i * 8][tx] = src[(long)(by + ty + i * 8) * 1024 + bx + tx];
  __syncthreads();
#pragma unroll
  for (int i = 0; i < 4; ++i)
    dst[(long)(bx + ty + i * 8) * 1024 + by + tx] = (bf16)t[tx][ty + i * 8];
}

// ------- GEMM: C[M,1024] = A[M,1024] @ Bt[1024,1024]^T + bias -----------------
template <bool A_IS_F32, bool OUT_F32>
__global__ __launch_bounds__(256) void gemm_bt(const void* __restrict__ Av,
                                               const bf16* __restrict__ Bt,
                                               const float* __restrict__ bias,
                                               void* __restrict__ Cv) {
  __shared__ __align__(16) bf16 As[128 * 32];
  __shared__ __align__(16) bf16 Bs[128 * 32];
  const int tid = threadIdx.x;
  const int l = tid & 63, w = tid >> 6;
  const int wr = w >> 1, wc = w & 1;
  const int lo = l & 15, g = l >> 4;
  const int m0 = blockIdx.x * 128;
  const int n0 = blockIdx.y * 128;
  const bf16* Ab = (const bf16*)Av + (long)m0 * 1024;
  const float* Af = (const float*)Av + (long)m0 * 1024;
  const bf16* Bb = Bt + (long)n0 * 1024;
  const int srow = tid >> 2;
  const int schunk = (tid & 3) * 8;
  f32x4 acc[4][4] = {};
  for (int k0 = 0; k0 < 1024; k0 += 32) {
    __syncthreads();
    if constexpr (A_IS_F32) {
#pragma unroll
      for (int h = 0; h < 2; ++h) {
        const float* p = Af + (long)(srow + h * 64) * 1024 + k0 + schunk;
        f32x4 u0 = *(const f32x4*)p;
        f32x4 u1 = *(const f32x4*)(p + 4);
        bf16x8 vv;
#pragma unroll
        for (int e = 0; e < 4; ++e) {
          vv[e] = (bf16)u0[e];
          vv[4 + e] = (bf16)u1[e];
        }
        *(bf16x8*)&As[h * 2048 + tid * 8] = vv;
      }
    } else {
      gload_lds16(Ab + (long)srow * 1024 + k0 + schunk, As + tid * 8);
      gload_lds16(Ab + (long)(srow + 64) * 1024 + k0 + schunk, As + 2048 + tid * 8);
    }
    gload_lds16(Bb + (long)srow * 1024 + k0 + schunk, Bs + tid * 8);
    gload_lds16(Bb + (long)(srow + 64) * 1024 + k0 + schunk, Bs + 2048 + tid * 8);
    __syncthreads();
    bf16x8 af[4], bfr[4];
#pragma unroll
    for (int m = 0; m < 4; ++m)
      af[m] = *(const bf16x8*)&As[(wr * 64 + m * 16 + lo) * 32 + g * 8];
#pragma unroll
    for (int n = 0; n < 4; ++n)
      bfr[n] = *(const bf16x8*)&Bs[(wc * 64 + n * 16 + lo) * 32 + g * 8];
#pragma unroll
    for (int m = 0; m < 4; ++m)
#pragma unroll
      for (int n = 0; n < 4; ++n)
        acc[m][n] = MFMA_BF16(af[m], bfr[n], acc[m][n]);
  }
#pragma unroll
  for (int n = 0; n < 4; ++n) {
    const int col = n0 + wc * 64 + n * 16 + lo;
    const float bv = bias[col];
#pragma unroll
    for (int m = 0; m < 4; ++m) {
      const long row0 = m0 + wr * 64 + m * 16 + g * 4;
#pragma unroll
      for (int j = 0; j < 4; ++j) {
        if constexpr (OUT_F32)
          ((float*)Cv)[(row0 + j) * 1024 + col] = acc[m][n][j] + bv;
        else
          ((bf16*)Cv)[(row0 + j) * 1024 + col] = (bf16)(acc[m][n][j] + bv);
      }
    }
  }
}

// ---------------- flash attention, Q=K=V = proj head panel [2048,64] ----------
// Swapped QK^T: mfma(K, Q) -> S^T[kv][q], stats lane-local for q = lo.
// P staged to LDS with pad-66 + 16B-chunk XOR swizzle (conflict-free writes).
__global__ __launch_bounds__(256) void attn(const bf16* __restrict__ proj,
                                            bf16* __restrict__ merged) {
  __shared__ __align__(16) bf16 Vt[64][66];        // [d][kv], pad 66 (33 dw/row)
  __shared__ __align__(16) bf16 Plds[4][32][66];   // [wave][q][kv swizzled]
  const int bid = blockIdx.x;
  const int qb = bid & 15;
  const int h = (bid >> 4) & 15;
  const int b = bid >> 8;
  const bf16* P = proj + (long)b * 2097152 + (long)h * 131072;  // [2048][64]
  const int tid = threadIdx.x;
  const int w = tid >> 6, l = tid & 63;
  const int lo = l & 15, g = l >> 4;
  const int qrow = qb * 128 + w * 32;

  // Q fragments, scaled by (1/sqrt(dk)) * log2(e): softmax runs in exp2 domain
  const float QSCALE = 0.125f * 1.44269504088896f;
  bf16x8 qa[2][2];
#pragma unroll
  for (int m = 0; m < 2; ++m)
#pragma unroll
    for (int ks = 0; ks < 2; ++ks) {
      bf16x8 t = *(const bf16x8*)&P[(long)(qrow + m * 16 + lo) * 64 + ks * 32 + g * 8];
#pragma unroll
      for (int e = 0; e < 8; ++e) t[e] = (bf16)((float)t[e] * QSCALE);
      qa[m][ks] = t;
    }

  f32x4 o[2][4] = {};
  float mq[2] = {-1e30f, -1e30f};  // running max (log2 domain) for q = m*16+lo
  float lq[2] = {0.f, 0.f};

  const int skv = tid >> 3;  // 0..31
  const int sc = tid & 7;    // d-chunk 0..7

  for (int kv0 = 0; kv0 < 2048; kv0 += 64) {
    __syncthreads();  // all waves done reading previous Vt
    // stage V^T: Vt[d][kv] = V[kv0+kv][d]
#pragma unroll
    for (int it = 0; it < 2; ++it) {
      const int kv = skv + it * 32;
      bf16x8 v = *(const bf16x8*)&P[(long)(kv0 + kv) * 64 + sc * 8];
#pragma unroll
      for (int e = 0; e < 8; ++e) Vt[sc * 8 + e][kv] = v[e];
    }
    __syncthreads();

    // S^T = K (Q*scale)^T : s[m][kt], C row = kv-in-tile (g*4+j), col = q = lo
    f32x4 s[2][4] = {};
#pragma unroll
    for (int kt = 0; kt < 4; ++kt)
#pragma unroll
      for (int ks = 0; ks < 2; ++ks) {
        bf16x8 kb = *(const bf16x8*)&P[(long)(kv0 + kt * 16 + lo) * 64 + ks * 32 + g * 8];
        s[0][kt] = MFMA_BF16(kb, qa[0][ks], s[0][kt]);
        s[1][kt] = MFMA_BF16(kb, qa[1][ks], s[1][kt]);
      }

    // online softmax: lane owns q = m*16+lo, holds kv = kt*16 + g*4 + j
#pragma unroll
    for (int m = 0; m < 2; ++m) {
      float mx = -1e30f;
#pragma unroll
      for (int kt = 0; kt < 4; ++kt)
#pragma unroll
        for (int j = 0; j < 4; ++j) mx = fmaxf(mx, s[m][kt][j]);
      mx = fmaxf(mx, __shfl_xor(mx, 16));
      mx = fmaxf(mx, __shfl_xor(mx, 32));
      const float mnew = fmaxf(mq[m], mx);
      const float corr = EXP2F(mq[m] - mnew);
      mq[m] = mnew;
      float ps = 0.f;
#pragma unroll
      for (int kt = 0; kt < 4; ++kt)
#pragma unroll
        for (int j = 0; j < 4; ++j) {
          const float p = EXP2F(s[m][kt][j] - mnew);
          s[m][kt][j] = p;
          ps += p;
        }
      ps += __shfl_xor(ps, 16);
      ps += __shfl_xor(ps, 32);
      lq[m] = lq[m] * corr + ps;
      // write P^T->P: row = m*16+lo, col = swizzled(kv), kv = kt*16+g*4+j
      // chunk cc = kt*2 + (g>>1), cc' = cc ^ (lo&3); in-chunk = (g&1)*4+j
#pragma unroll
      for (int kt = 0; kt < 4; ++kt)
#pragma unroll
        for (int j = 0; j < 4; ++j)
          Plds[w][m * 16 + lo][(((kt * 2 + (g >> 1)) ^ (lo & 3)) << 3) + ((g & 1) << 2) + j] =
              (bf16)s[m][kt][j];
      // rescale o rows (row = g*4+j) with corr of q-row g*4+j (held by lane lo'=g*4+j)
#pragma unroll
      for (int j = 0; j < 4; ++j) {
        const float cj = __shfl(corr, g * 4 + j, 16);
#pragma unroll
        for (int n = 0; n < 4; ++n) o[m][n][j] *= cj;
      }
    }

    // O += P V  (A from Plds with matching swizzle, B from Vt)
#pragma unroll
    for (int ks = 0; ks < 2; ++ks) {
      const int pc = ((ks * 4 + g) ^ (lo & 3)) << 3;  // swizzled chunk base
      bf16x8 pa0 = *(const bf16x8*)&Plds[w][lo][pc];
      bf16x8 pa1 = *(const bf16x8*)&Plds[w][16 + lo][pc];
#pragma unroll
      for (int n = 0; n < 4; ++n) {
        bf16x8 vb = *(const bf16x8*)&Vt[n * 16 + lo][ks * 32 + g * 8];
        o[0][n] = MFMA_BF16(pa0, vb, o[0][n]);
        o[1][n] = MFMA_BF16(pa1, vb, o[1][n]);
      }
    }
  }

  // finalize + store into merged layout: merged[b][sq][h*64 + d]
  bf16* mb = merged + (long)b * 2097152 + h * 64;
#pragma unroll
  for (int m = 0; m < 2; ++m)
#pragma unroll
    for (int j = 0; j < 4; ++j) {
      const float lj = __shfl(lq[m], g * 4 + j, 16);
      const float inv = 1.0f / lj;
      const int sq = qrow + m * 16 + g * 4 + j;
#pragma unroll
      for (int n = 0; n < 4; ++n)
        mb[(long)sq * 1024 + n * 16 + lo] = (bf16)(o[m][n][j] * inv);
    }
}

extern "C" void kernel_launch(void* const* d_in, const int* in_sizes, int n_in,
                              void* d_out, int out_size, void* d_ws, size_t ws_size,
                              hipStream_t stream) {
  const float* x = (const float*)d_in[0];
  const float* Wqkv = (const float*)d_in[1];
  const float* bqkv = (const float*)d_in[2];
  const float* Wo = (const float*)d_in[3];
  const float* bo = (const float*)d_in[4];
  float* out = (float*)d_out;

  char* ws = (char*)d_ws;
  bf16* proj = (bf16*)(ws);                     // 16.78 MB  [4][2048][1024]
  bf16* merged = (bf16*)(ws + 16777216);        // 16.78 MB  [4][2048][1024]
  bf16* WqkvT = (bf16*)(ws + 33554432);         // 2 MB      [n][k]
  bf16* WoT = (bf16*)(ws + 35651584);           // 2 MB      [n][k]

  transcvt2<<<dim3(32, 32, 2), dim3(32, 8), 0, stream>>>(Wqkv, WqkvT, Wo, WoT);
  gemm_bt<true, false><<<dim3(64, 8), dim3(256), 0, stream>>>(x, WqkvT, bqkv, proj);
  attn<<<dim3(1024), dim3(256), 0, stream>>>(proj, merged);
  gemm_bt<false, true><<<dim3(64, 8), dim3(256), 0, stream>>>(merged, WoT, bo, out);
}

// Round 7
// 326.956 us; speedup vs baseline: 1.4335x; 1.0514x over previous
//
#include <hip/hip_runtime.h>
#include <hip/hip_bf16.h>

typedef __bf16 bf16;
typedef __attribute__((ext_vector_type(8))) __bf16 bf16x8;
typedef __attribute__((ext_vector_type(4))) float f32x4;
typedef __attribute__((ext_vector_type(16))) float f32x16;

#define MFMA_BF16(a, b, c) __builtin_amdgcn_mfma_f32_16x16x32_bf16((a), (b), (c), 0, 0, 0)
#define MFMA32(a, b, c) __builtin_amdgcn_mfma_f32_32x32x16_bf16((a), (b), (c), 0, 0, 0)
#define EXP2F(x) __builtin_amdgcn_exp2f(x)

__device__ __forceinline__ void gload_lds16(const bf16* g, bf16* l) {
  __builtin_amdgcn_global_load_lds(
      (__attribute__((address_space(1))) void*)(g),
      (__attribute__((address_space(3))) void*)(l), 16, 0, 0);
}

__device__ __forceinline__ int cvtpk(float lo, float hi) {
  int r;
  asm("v_cvt_pk_bf16_f32 %0, %1, %2" : "=v"(r) : "v"(lo), "v"(hi));
  return r;
}

// ------- transpose + f32->bf16 convert of both weight matrices (1024x1024) ----
__global__ void transcvt2(const float* __restrict__ W0, bf16* __restrict__ T0,
                          const float* __restrict__ W1, bf16* __restrict__ T1) {
  const float* src = blockIdx.z ? W1 : W0;
  bf16* dst = blockIdx.z ? T1 : T0;
  __shared__ float t[32][33];
  const int bx = blockIdx.x * 32, by = blockIdx.y * 32;
  const int tx = threadIdx.x, ty = threadIdx.y;
#pragma unroll
  for (int i = 0; i < 4; ++i)
    t[ty + i * 8][tx] = src[(long)(by + ty + i * 8) * 1024 + bx + tx];
  __syncthreads();
#pragma unroll
  for (int i = 0; i < 4; ++i)
    dst[(long)(bx + ty + i * 8) * 1024 + by + tx] = (bf16)t[tx][ty + i * 8];
}

// ------- GEMM: C[M,1024] = A[M,1024] @ Bt[1024,1024]^T + bias -----------------
template <bool A_IS_F32, bool OUT_F32>
__global__ __launch_bounds__(256) void gemm_bt(const void* __restrict__ Av,
                                               const bf16* __restrict__ Bt,
                                               const float* __restrict__ bias,
                                               void* __restrict__ Cv) {
  __shared__ __align__(16) bf16 As[128 * 32];
  __shared__ __align__(16) bf16 Bs[128 * 32];
  const int tid = threadIdx.x;
  const int l = tid & 63, w = tid >> 6;
  const int wr = w >> 1, wc = w & 1;
  const int lo = l & 15, g = l >> 4;
  const int m0 = blockIdx.x * 128;
  const int n0 = blockIdx.y * 128;
  const bf16* Ab = (const bf16*)Av + (long)m0 * 1024;
  const float* Af = (const float*)Av + (long)m0 * 1024;
  const bf16* Bb = Bt + (long)n0 * 1024;
  const int srow = tid >> 2;
  const int schunk = (tid & 3) * 8;
  f32x4 acc[4][4] = {};
  for (int k0 = 0; k0 < 1024; k0 += 32) {
    __syncthreads();
    if constexpr (A_IS_F32) {
#pragma unroll
      for (int h = 0; h < 2; ++h) {
        const float* p = Af + (long)(srow + h * 64) * 1024 + k0 + schunk;
        f32x4 u0 = *(const f32x4*)p;
        f32x4 u1 = *(const f32x4*)(p + 4);
        bf16x8 vv;
#pragma unroll
        for (int e = 0; e < 4; ++e) {
          vv[e] = (bf16)u0[e];
          vv[4 + e] = (bf16)u1[e];
        }
        *(bf16x8*)&As[h * 2048 + tid * 8] = vv;
      }
    } else {
      gload_lds16(Ab + (long)srow * 1024 + k0 + schunk, As + tid * 8);
      gload_lds16(Ab + (long)(srow + 64) * 1024 + k0 + schunk, As + 2048 + tid * 8);
    }
    gload_lds16(Bb + (long)srow * 1024 + k0 + schunk, Bs + tid * 8);
    gload_lds16(Bb + (long)(srow + 64) * 1024 + k0 + schunk, Bs + 2048 + tid * 8);
    __syncthreads();
    bf16x8 af[4], bfr[4];
#pragma unroll
    for (int m = 0; m < 4; ++m)
      af[m] = *(const bf16x8*)&As[(wr * 64 + m * 16 + lo) * 32 + g * 8];
#pragma unroll
    for (int n = 0; n < 4; ++n)
      bfr[n] = *(const bf16x8*)&Bs[(wc * 64 + n * 16 + lo) * 32 + g * 8];
#pragma unroll
    for (int m = 0; m < 4; ++m)
#pragma unroll
      for (int n = 0; n < 4; ++n)
        acc[m][n] = MFMA_BF16(af[m], bfr[n], acc[m][n]);
  }
#pragma unroll
  for (int n = 0; n < 4; ++n) {
    const int col = n0 + wc * 64 + n * 16 + lo;
    const float bv = bias[col];
#pragma unroll
    for (int m = 0; m < 4; ++m) {
      const long row0 = m0 + wr * 64 + m * 16 + g * 4;
#pragma unroll
      for (int j = 0; j < 4; ++j) {
        if constexpr (OUT_F32)
          ((float*)Cv)[(row0 + j) * 1024 + col] = acc[m][n][j] + bv;
        else
          ((bf16*)Cv)[(row0 + j) * 1024 + col] = (bf16)(acc[m][n][j] + bv);
      }
    }
  }
}

// ---------------- flash attention, 32x32 MFMA, register softmax ---------------
// Q=K=V = proj head panel [2048,64]. 4 waves/block, each wave 32 q-rows.
// S^T = mfma32(K,Q): col=l&31=q (stats lane-local), rows=kv.
// P -> PV B-frag in-register via cvt_pk + shfl_xor(32) half-exchange.
// O^T = mfma32(V^T, P^T): col=q, rescale lane-local. LDS: only Vt dbuf.
__global__ __launch_bounds__(256) void attn(const bf16* __restrict__ proj,
                                            bf16* __restrict__ merged) {
  __shared__ __align__(16) bf16 Vt[2][64][34];  // [buf][d][kv], 17-dw row stride
  const int bid = blockIdx.x;
  const int qb = bid & 15;
  const int hh = (bid >> 4) & 15;
  const int b = bid >> 8;
  const bf16* P = proj + (long)b * 2097152 + (long)hh * 131072;  // [2048][64]
  const int tid = threadIdx.x;
  const int w = tid >> 6, l = tid & 63;
  const int l31 = l & 31;
  const bool hi = (l >= 32);
  const int hf = hi ? 1 : 0;
  const int qrow = qb * 128 + w * 32;

  // staging map: thread -> (kv = tid>>3, d-chunk = (tid&7)*8)
  const int skv = tid >> 3;
  const int sc = (tid & 7) * 8;

  // Q B-frag (col=q=l31, k = hf*8+e + 16s), scaled by 0.125*log2(e)
  const float QSCALE = 0.125f * 1.44269504088896f;
  bf16x8 qf[4];
#pragma unroll
  for (int s = 0; s < 4; ++s) {
    bf16x8 t = *(const bf16x8*)&P[(long)(qrow + l31) * 64 + s * 16 + hf * 8];
#pragma unroll
    for (int e = 0; e < 8; ++e) t[e] = (bf16)((float)t[e] * QSCALE);
    qf[s] = t;
  }

  f32x16 o0 = {}, o1 = {};
  float mq = -1e30f, lq = 0.f;

  // prologue: stage V-tile 0 into buf0; load K-tile 0 (kA)
  bf16x8 kA[4], kB[4];
  {
    bf16x8 v = *(const bf16x8*)&P[(long)skv * 64 + sc];
#pragma unroll
    for (int e = 0; e < 8; ++e) Vt[0][sc + e][skv] = v[e];
  }
#pragma unroll
  for (int s = 0; s < 4; ++s)
    kA[s] = *(const bf16x8*)&P[(long)l31 * 64 + s * 16 + hf * 8];
  __syncthreads();

  for (int t2 = 0; t2 < 32; ++t2) {
#pragma unroll
    for (int ph = 0; ph < 2; ++ph) {
      const int t = t2 * 2 + ph;
      const int tn = (t < 63) ? t + 1 : 63;
      // 1) issue V(t+1) load early (per-thread b128)
      bf16x8 vnx = *(const bf16x8*)&P[((long)tn * 32 + skv) * 64 + sc];
      // 2) S^T = K Q^T  (A = K-frag rows kv=l31, B = Q cols q=l31)
      f32x16 s;
      if (ph == 0) {
        s = MFMA32(kA[0], qf[0], f32x16{});
        s = MFMA32(kA[1], qf[1], s);
        s = MFMA32(kA[2], qf[2], s);
        s = MFMA32(kA[3], qf[3], s);
      } else {
        s = MFMA32(kB[0], qf[0], f32x16{});
        s = MFMA32(kB[1], qf[1], s);
        s = MFMA32(kB[2], qf[2], s);
        s = MFMA32(kB[3], qf[3], s);
      }
      // 3) prefetch K(t+1)
#pragma unroll
      for (int sx = 0; sx < 4; ++sx) {
        bf16x8 kv8 = *(const bf16x8*)&P[((long)tn * 32 + l31) * 64 + sx * 16 + hf * 8];
        if (ph == 0) kB[sx] = kv8; else kA[sx] = kv8;
      }
      // 4) online softmax (stats lane-local, q = l31; rows split l<->l+32)
      float mx = s[0];
#pragma unroll
      for (int i = 1; i < 16; ++i) mx = fmaxf(mx, s[i]);
      mx = fmaxf(mx, __shfl_xor(mx, 32));
      if (__any(mx > mq)) {
        const float mnew = fmaxf(mq, mx);
        const float corr = EXP2F(mq - mnew);
        mq = mnew;
        lq *= corr;
#pragma unroll
        for (int i = 0; i < 16; ++i) { o0[i] *= corr; o1[i] *= corr; }
      }
      float ps = 0.f;
#pragma unroll
      for (int i = 0; i < 16; ++i) {
        const float p = EXP2F(s[i] - mq);
        s[i] = p;
        ps += p;
      }
      ps += __shfl_xor(ps, 32);
      lq += ps;
      // 5) pack P -> PV B-fragments (cvt_pk pairs; half-exchange via shfl_xor)
      // lane holds kv pairs: pk0={0,1}+4hf pk1={2,3}+4hf pk2={8,9}+4hf pk3={10,11}+4hf
      //                      pk4={16,17}+4hf pk5={18,19}+4hf pk6={24,25}+4hf pk7={26,27}+4hf
      // B-frag ks: dword e2 = kv {ks*16 + hf*8 + 2*e2, +1}
      const int pk0 = cvtpk(s[0], s[1]), pk1 = cvtpk(s[2], s[3]);
      const int pk2 = cvtpk(s[4], s[5]), pk3 = cvtpk(s[6], s[7]);
      const int pk4 = cvtpk(s[8], s[9]), pk5 = cvtpk(s[10], s[11]);
      const int pk6 = cvtpk(s[12], s[13]), pk7 = cvtpk(s[14], s[15]);
      const int x0 = __shfl_xor(pk0, 32), x2 = __shfl_xor(pk2, 32);
      const int x1 = __shfl_xor(pk1, 32), x3 = __shfl_xor(pk3, 32);
      const int x4 = __shfl_xor(pk4, 32), x6 = __shfl_xor(pk6, 32);
      const int x5 = __shfl_xor(pk5, 32), x7 = __shfl_xor(pk7, 32);
      int bi0[4], bi1[4];
      bi0[0] = hi ? x2 : pk0;   // {pk0_lo, pk2_lo}
      bi0[1] = hi ? x3 : pk1;   // {pk1_lo, pk3_lo}
      bi0[2] = hi ? pk2 : x0;   // {pk0_hi, pk2_hi}
      bi0[3] = hi ? pk3 : x1;   // {pk1_hi, pk3_hi}
      bi1[0] = hi ? x6 : pk4;
      bi1[1] = hi ? x7 : pk5;
      bi1[2] = hi ? pk6 : x4;
      bi1[3] = hi ? pk7 : x5;
      bf16x8 pb0 = *(bf16x8*)bi0;
      bf16x8 pb1 = *(bf16x8*)bi1;
      // 6) O^T += V^T P^T   (A = V^T from LDS, B = P-frag; col=q)
      {
        bf16x8 va;
        va = *(const bf16x8*)&Vt[ph][l31][hf * 8];
        o0 = MFMA32(va, pb0, o0);
        va = *(const bf16x8*)&Vt[ph][l31][16 + hf * 8];
        o0 = MFMA32(va, pb1, o0);
        va = *(const bf16x8*)&Vt[ph][32 + l31][hf * 8];
        o1 = MFMA32(va, pb0, o1);
        va = *(const bf16x8*)&Vt[ph][32 + l31][16 + hf * 8];
        o1 = MFMA32(va, pb1, o1);
      }
      // 7) write V(t+1) into the other buffer, then barrier
#pragma unroll
      for (int e = 0; e < 8; ++e) Vt[ph ^ 1][sc + e][skv] = vnx[e];
      __syncthreads();
    }
  }

  // epilogue: O^T[d][q]/lq -> merged[b][qrow+q][hh*64 + d]
  const float inv = 1.0f / lq;
  bf16* mb = merged + (long)b * 2097152 + hh * 64;
  const long rowoff = (long)(qrow + l31) * 1024;
  const int dbase[8] = {0, 2, 8, 10, 16, 18, 24, 26};
#pragma unroll
  for (int r = 0; r < 8; ++r) {
    const int d = dbase[r] + 4 * hf;
    *(int*)&mb[rowoff + d] = cvtpk(o0[2 * r] * inv, o0[2 * r + 1] * inv);
    *(int*)&mb[rowoff + 32 + d] = cvtpk(o1[2 * r] * inv, o1[2 * r + 1] * inv);
  }
}

extern "C" void kernel_launch(void* const* d_in, const int* in_sizes, int n_in,
                              void* d_out, int out_size, void* d_ws, size_t ws_size,
                              hipStream_t stream) {
  const float* x = (const float*)d_in[0];
  const float* Wqkv = (const float*)d_in[1];
  const float* bqkv = (const float*)d_in[2];
  const float* Wo = (const float*)d_in[3];
  const float* bo = (const float*)d_in[4];
  float* out = (float*)d_out;

  char* ws = (char*)d_ws;
  bf16* proj = (bf16*)(ws);                     // 16.78 MB  [4][2048][1024]
  bf16* merged = (bf16*)(ws + 16777216);        // 16.78 MB  [4][2048][1024]
  bf16* WqkvT = (bf16*)(ws + 33554432);         // 2 MB      [n][k]
  bf16* WoT = (bf16*)(ws + 35651584);           // 2 MB      [n][k]

  transcvt2<<<dim3(32, 32, 2), dim3(32, 8), 0, stream>>>(Wqkv, WqkvT, Wo, WoT);
  gemm_bt<true, false><<<dim3(64, 8), dim3(256), 0, stream>>>(x, WqkvT, bqkv, proj);
  attn<<<dim3(1024), dim3(256), 0, stream>>>(proj, merged);
  gemm_bt<false, true><<<dim3(64, 8), dim3(256), 0, stream>>>(merged, WoT, bo, out);
}

// Round 9
// 326.783 us; speedup vs baseline: 1.4343x; 1.0005x over previous
//
#include <hip/hip_runtime.h>
#include <hip/hip_bf16.h>

typedef __bf16 bf16;
typedef __attribute__((ext_vector_type(8))) __bf16 bf16x8;
typedef __attribute__((ext_vector_type(4))) float f32x4;
typedef __attribute__((ext_vector_type(16))) float f32x16;
typedef __attribute__((ext_vector_type(4))) unsigned short u16x4;

#define MFMA_BF16(a, b, c) __builtin_amdgcn_mfma_f32_16x16x32_bf16((a), (b), (c), 0, 0, 0)
#define MFMA32(a, b, c) __builtin_amdgcn_mfma_f32_32x32x16_bf16((a), (b), (c), 0, 0, 0)
#define EXP2F(x) __builtin_amdgcn_exp2f(x)

__device__ __forceinline__ void gload_lds16(const bf16* g, bf16* l) {
  __builtin_amdgcn_global_load_lds(
      (__attribute__((address_space(1))) void*)(g),
      (__attribute__((address_space(3))) void*)(l), 16, 0, 0);
}

__device__ __forceinline__ int cvtpk(float lo, float hi) {
  int r;
  asm("v_cvt_pk_bf16_f32 %0, %1, %2" : "=v"(r) : "v"(lo), "v"(hi));
  return r;
}
__device__ __forceinline__ void plswap(int& a, int& b) {
  asm volatile("v_permlane32_swap_b32 %0, %1" : "+v"(a), "+v"(b));
}
// direction-agnostic half-wave exchange: returns {own,partner} combined
__device__ __forceinline__ float swap_max(float x) {
  int u = __float_as_int(x), v;
  asm volatile("v_mov_b32 %0, %1" : "=v"(v) : "v"(u));  // force distinct reg
  plswap(u, v);
  return fmaxf(__int_as_float(u), __int_as_float(v));
}
__device__ __forceinline__ float swap_add(float x) {
  int u = __float_as_int(x), v;
  asm volatile("v_mov_b32 %0, %1" : "=v"(v) : "v"(u));
  plswap(u, v);
  return __int_as_float(u) + __int_as_float(v);
}

// ------- transpose + f32->bf16 convert of both weight matrices (1024x1024) ----
__global__ void transcvt2(const float* __restrict__ W0, bf16* __restrict__ T0,
                          const float* __restrict__ W1, bf16* __restrict__ T1) {
  const float* src = blockIdx.z ? W1 : W0;
  bf16* dst = blockIdx.z ? T1 : T0;
  __shared__ float t[32][33];
  const int bx = blockIdx.x * 32, by = blockIdx.y * 32;
  const int tx = threadIdx.x, ty = threadIdx.y;
#pragma unroll
  for (int i = 0; i < 4; ++i)
    t[ty + i * 8][tx] = src[(long)(by + ty + i * 8) * 1024 + bx + tx];
  __syncthreads();
#pragma unroll
  for (int i = 0; i < 4; ++i)
    dst[(long)(bx + ty + i * 8) * 1024 + by + tx] = (bf16)t[tx][ty + i * 8];
}

// ------- GEMM: C[M,1024] = A[M,1024] @ Bt[1024,1024]^T + bias -----------------
template <bool A_IS_F32, bool OUT_F32>
__global__ __launch_bounds__(256) void gemm_bt(const void* __restrict__ Av,
                                               const bf16* __restrict__ Bt,
                                               const float* __restrict__ bias,
                                               void* __restrict__ Cv) {
  __shared__ __align__(16) bf16 As[128 * 32];
  __shared__ __align__(16) bf16 Bs[128 * 32];
  const int tid = threadIdx.x;
  const int l = tid & 63, w = tid >> 6;
  const int wr = w >> 1, wc = w & 1;
  const int lo = l & 15, g = l >> 4;
  const int m0 = blockIdx.x * 128;
  const int n0 = blockIdx.y * 128;
  const bf16* Ab = (const bf16*)Av + (long)m0 * 1024;
  const float* Af = (const float*)Av + (long)m0 * 1024;
  const bf16* Bb = Bt + (long)n0 * 1024;
  const int srow = tid >> 2;
  const int schunk = (tid & 3) * 8;
  f32x4 acc[4][4] = {};
  for (int k0 = 0; k0 < 1024; k0 += 32) {
    __syncthreads();
    if constexpr (A_IS_F32) {
#pragma unroll
      for (int h = 0; h < 2; ++h) {
        const float* p = Af + (long)(srow + h * 64) * 1024 + k0 + schunk;
        f32x4 u0 = *(const f32x4*)p;
        f32x4 u1 = *(const f32x4*)(p + 4);
        bf16x8 vv;
#pragma unroll
        for (int e = 0; e < 4; ++e) {
          vv[e] = (bf16)u0[e];
          vv[4 + e] = (bf16)u1[e];
        }
        *(bf16x8*)&As[h * 2048 + tid * 8] = vv;
      }
    } else {
      gload_lds16(Ab + (long)srow * 1024 + k0 + schunk, As + tid * 8);
      gload_lds16(Ab + (long)(srow + 64) * 1024 + k0 + schunk, As + 2048 + tid * 8);
    }
    gload_lds16(Bb + (long)srow * 1024 + k0 + schunk, Bs + tid * 8);
    gload_lds16(Bb + (long)(srow + 64) * 1024 + k0 + schunk, Bs + 2048 + tid * 8);
    __syncthreads();
    bf16x8 af[4], bfr[4];
#pragma unroll
    for (int m = 0; m < 4; ++m)
      af[m] = *(const bf16x8*)&As[(wr * 64 + m * 16 + lo) * 32 + g * 8];
#pragma unroll
    for (int n = 0; n < 4; ++n)
      bfr[n] = *(const bf16x8*)&Bs[(wc * 64 + n * 16 + lo) * 32 + g * 8];
#pragma unroll
    for (int m = 0; m < 4; ++m)
#pragma unroll
      for (int n = 0; n < 4; ++n)
        acc[m][n] = MFMA_BF16(af[m], bfr[n], acc[m][n]);
  }
#pragma unroll
  for (int n = 0; n < 4; ++n) {
    const int col = n0 + wc * 64 + n * 16 + lo;
    const float bv = bias[col];
#pragma unroll
    for (int m = 0; m < 4; ++m) {
      const long row0 = m0 + wr * 64 + m * 16 + g * 4;
#pragma unroll
      for (int j = 0; j < 4; ++j) {
        if constexpr (OUT_F32)
          ((float*)Cv)[(row0 + j) * 1024 + col] = acc[m][n][j] + bv;
        else
          ((bf16*)Cv)[(row0 + j) * 1024 + col] = (bf16)(acc[m][n][j] + bv);
      }
    }
  }
}

// ---------------- flash attention, 32x32 MFMA, register softmax ---------------
// Q=K=V = proj head panel [2048,64]. 4 waves/block, each wave 32 q-rows.
// S^T = mfma32(K,Q): col=l&31=q (stats lane-local), rows=kv.
// P -> PV B-frag in-register via cvt_pk + permlane32_swap (runtime dir probe).
// O^T = mfma32(V^T, P^T): col=q, rescale lane-local.
// LDS: only Vt dbuf; staged as packed b32 kv-pairs (2-way banks, free).
__global__ __launch_bounds__(256) void attn(const bf16* __restrict__ proj,
                                            bf16* __restrict__ merged) {
  __shared__ __align__(16) bf16 Vt[2][64][34];  // [buf][d][kv], 17-dw row stride
  const int bid = blockIdx.x;
  const int qb = bid & 15;
  const int hh = (bid >> 4) & 15;
  const int b = bid >> 8;
  const bf16* P = proj + (long)b * 2097152 + (long)hh * 131072;  // [2048][64]
  const int tid = threadIdx.x;
  const int w = tid >> 6, l = tid & 63;
  const int l31 = l & 31;
  const int hf = l >> 5;
  const int qrow = qb * 128 + w * 32;

  // staging map: thread -> kv-pair kvp = tid>>4 (kv 2kvp,2kvp+1), d-chunk dc*4
  const int kvp = tid >> 4;
  const int dc = tid & 15;
  int* VtI = (int*)Vt;  // [2][64][17]

  // permlane direction probe (one-time): dir1 <=> vdst-hi <-> vsrc-lo
  int pu = l, pv;
  asm volatile("v_mov_b32 %0, %1" : "=v"(pv) : "v"(pu));
  plswap(pu, pv);
  const bool dir1 = (__shfl(pu, 33, 64) == 1);

  // Q B-frag (col=q=l31, k = hf*8+e + 16s), scaled by 0.125*log2(e)
  const float QSCALE = 0.125f * 1.44269504088896f;
  bf16x8 qf[4];
#pragma unroll
  for (int s = 0; s < 4; ++s) {
    bf16x8 t = *(const bf16x8*)&P[(long)(qrow + l31) * 64 + s * 16 + hf * 8];
#pragma unroll
    for (int e = 0; e < 8; ++e) t[e] = (bf16)((float)t[e] * QSCALE);
    qf[s] = t;
  }

  f32x16 o0 = {}, o1 = {};
  float mq = -1e30f, lq = 0.f;

  // prologue: stage V-tile 0 into buf0 (packed b32 kv-pairs); load K-tile 0
  bf16x8 kA[4], kB[4];
  {
    u16x4 v0 = *(const u16x4*)&P[(long)(2 * kvp) * 64 + dc * 4];
    u16x4 v1 = *(const u16x4*)&P[(long)(2 * kvp + 1) * 64 + dc * 4];
#pragma unroll
    for (int dd = 0; dd < 4; ++dd)
      VtI[(dc * 4 + dd) * 17 + kvp] = ((int)v0[dd]) | (((int)v1[dd]) << 16);
  }
#pragma unroll
  for (int s = 0; s < 4; ++s)
    kA[s] = *(const bf16x8*)&P[(long)l31 * 64 + s * 16 + hf * 8];
  __syncthreads();

  for (int t2 = 0; t2 < 32; ++t2) {
#pragma unroll
    for (int ph = 0; ph < 2; ++ph) {
      const int t = t2 * 2 + ph;
      const int tn = (t < 63) ? t + 1 : 63;
      // 1) issue V(t+1) loads early (two b64 per thread, coalesced)
      u16x4 vn0 = *(const u16x4*)&P[((long)tn * 32 + 2 * kvp) * 64 + dc * 4];
      u16x4 vn1 = *(const u16x4*)&P[((long)tn * 32 + 2 * kvp + 1) * 64 + dc * 4];
      // 2) S^T = K Q^T  (A = K-frag rows kv=l31, B = Q cols q=l31)
      f32x16 s;
      if (ph == 0) {
        s = MFMA32(kA[0], qf[0], f32x16{});
        s = MFMA32(kA[1], qf[1], s);
        s = MFMA32(kA[2], qf[2], s);
        s = MFMA32(kA[3], qf[3], s);
      } else {
        s = MFMA32(kB[0], qf[0], f32x16{});
        s = MFMA32(kB[1], qf[1], s);
        s = MFMA32(kB[2], qf[2], s);
        s = MFMA32(kB[3], qf[3], s);
      }
      // 3) prefetch K(t+1)
#pragma unroll
      for (int sx = 0; sx < 4; ++sx) {
        bf16x8 kv8 = *(const bf16x8*)&P[((long)tn * 32 + l31) * 64 + sx * 16 + hf * 8];
        if (ph == 0) kB[sx] = kv8; else kA[sx] = kv8;
      }
      // 4) online softmax (stats lane-local, q = l31; rows split l<->l+32)
      float mx = s[0];
#pragma unroll
      for (int i = 1; i < 16; ++i) mx = fmaxf(mx, s[i]);
      mx = swap_max(mx);
      if (__any(mx > mq)) {
        const float mnew = fmaxf(mq, mx);
        const float corr = EXP2F(mq - mnew);
        mq = mnew;
        lq *= corr;
#pragma unroll
        for (int i = 0; i < 16; ++i) { o0[i] *= corr; o1[i] *= corr; }
      }
      float ps = 0.f;
#pragma unroll
      for (int i = 0; i < 16; ++i) {
        const float p = EXP2F(s[i] - mq);
        s[i] = p;
        ps += p;
      }
      ps = swap_add(ps);
      lq += ps;
      // 5) pack P -> PV B-fragments: cvt_pk pairs + permlane half-exchange
      // lane kv pairs: p0={0,1}+4hf p1={2,3}+4hf p2={8,9}+4hf p3={10,11}+4hf
      //                p4={16,17}+4hf ... p7={26,27}+4hf
      int p0 = cvtpk(s[0], s[1]), p1 = cvtpk(s[2], s[3]);
      int p2 = cvtpk(s[4], s[5]), p3 = cvtpk(s[6], s[7]);
      int p4 = cvtpk(s[8], s[9]), p5 = cvtpk(s[10], s[11]);
      int p6 = cvtpk(s[12], s[13]), p7 = cvtpk(s[14], s[15]);
      if (dir1) {
        plswap(p0, p2); plswap(p1, p3); plswap(p4, p6); plswap(p5, p7);
      } else {
        plswap(p2, p0); plswap(p3, p1); plswap(p6, p4); plswap(p7, p5);
      }
      int bi0[4] = {p0, p1, p2, p3};
      int bi1[4] = {p4, p5, p6, p7};
      bf16x8 pb0 = *(bf16x8*)bi0;
      bf16x8 pb1 = *(bf16x8*)bi1;
      // 6) O^T += V^T P^T   (A = V^T from LDS, B = P-frag; col=q)
      {
        bf16x8 va;
        va = *(const bf16x8*)&Vt[ph][l31][hf * 8];
        o0 = MFMA32(va, pb0, o0);
        va = *(const bf16x8*)&Vt[ph][l31][16 + hf * 8];
        o0 = MFMA32(va, pb1, o0);
        va = *(const bf16x8*)&Vt[ph][32 + l31][hf * 8];
        o1 = MFMA32(va, pb0, o1);
        va = *(const bf16x8*)&Vt[ph][32 + l31][16 + hf * 8];
        o1 = MFMA32(va, pb1, o1);
      }
      // 7) write V(t+1) into the other buffer (packed b32), then barrier
      {
        int* W = VtI + (ph ^ 1) * (64 * 17);
#pragma unroll
        for (int dd = 0; dd < 4; ++dd)
          W[(dc * 4 + dd) * 17 + kvp] = ((int)vn0[dd]) | (((int)vn1[dd]) << 16);
      }
      __syncthreads();
    }
  }

  // epilogue: O^T[d][q]/lq -> merged[b][qrow+q][hh*64 + d]
  const float inv = 1.0f / lq;
  bf16* mb = merged + (long)b * 2097152 + hh * 64;
  const long rowoff = (long)(qrow + l31) * 1024;
  const int dbase[8] = {0, 2, 8, 10, 16, 18, 24, 26};
#pragma unroll
  for (int r = 0; r < 8; ++r) {
    const int d = dbase[r] + 4 * hf;
    *(int*)&mb[rowoff + d] = cvtpk(o0[2 * r] * inv, o0[2 * r + 1] * inv);
    *(int*)&mb[rowoff + 32 + d] = cvtpk(o1[2 * r] * inv, o1[2 * r + 1] * inv);
  }
}

extern "C" void kernel_launch(void* const* d_in, const int* in_sizes, int n_in,
                              void* d_out, int out_size, void* d_ws, size_t ws_size,
                              hipStream_t stream) {
  const float* x = (const float*)d_in[0];
  const float* Wqkv = (const float*)d_in[1];
  const float* bqkv = (const float*)d_in[2];
  const float* Wo = (const float*)d_in[3];
  const float* bo = (const float*)d_in[4];
  float* out = (float*)d_out;

  char* ws = (char*)d_ws;
  bf16* proj = (bf16*)(ws);                     // 16.78 MB  [4][2048][1024]
  bf16* merged = (bf16*)(ws + 16777216);        // 16.78 MB  [4][2048][1024]
  bf16* WqkvT = (bf16*)(ws + 33554432);         // 2 MB      [n][k]
  bf16* WoT = (bf16*)(ws + 35651584);           // 2 MB      [n][k]

  transcvt2<<<dim3(32, 32, 2), dim3(32, 8), 0, stream>>>(Wqkv, WqkvT, Wo, WoT);
  gemm_bt<true, false><<<dim3(64, 8), dim3(256), 0, stream>>>(x, WqkvT, bqkv, proj);
  attn<<<dim3(1024), dim3(256), 0, stream>>>(proj, merged);
  gemm_bt<false, true><<<dim3(64, 8), dim3(256), 0, stream>>>(merged, WoT, bo, out);
}

// Round 10
// 309.210 us; speedup vs baseline: 1.5158x; 1.0568x over previous
//
#include <hip/hip_runtime.h>
#include <hip/hip_bf16.h>

typedef __bf16 bf16;
typedef __attribute__((ext_vector_type(8))) __bf16 bf16x8;
typedef __attribute__((ext_vector_type(4))) float f32x4;
typedef __attribute__((ext_vector_type(16))) float f32x16;
typedef __attribute__((ext_vector_type(4))) unsigned short u16x4;

#define MFMA_BF16(a, b, c) __builtin_amdgcn_mfma_f32_16x16x32_bf16((a), (b), (c), 0, 0, 0)
#define MFMA32(a, b, c) __builtin_amdgcn_mfma_f32_32x32x16_bf16((a), (b), (c), 0, 0, 0)
#define EXP2F(x) __builtin_amdgcn_exp2f(x)

__device__ __forceinline__ void gload_lds16(const bf16* g, bf16* l) {
  __builtin_amdgcn_global_load_lds(
      (__attribute__((address_space(1))) void*)(g),
      (__attribute__((address_space(3))) void*)(l), 16, 0, 0);
}

__device__ __forceinline__ int cvtpk(float lo, float hi) {
  int r;
  asm("v_cvt_pk_bf16_f32 %0, %1, %2" : "=v"(r) : "v"(lo), "v"(hi));
  return r;
}
__device__ __forceinline__ void plswap(int& a, int& b) {
  asm volatile("v_permlane32_swap_b32 %0, %1" : "+v"(a), "+v"(b));
}
// direction-agnostic half-wave exchange: returns {own,partner} combined
__device__ __forceinline__ float swap_max(float x) {
  int u = __float_as_int(x), v;
  asm volatile("v_mov_b32 %0, %1" : "=v"(v) : "v"(u));  // force distinct reg
  plswap(u, v);
  return fmaxf(__int_as_float(u), __int_as_float(v));
}
__device__ __forceinline__ float swap_add(float x) {
  int u = __float_as_int(x), v;
  asm volatile("v_mov_b32 %0, %1" : "=v"(v) : "v"(u));
  plswap(u, v);
  return __int_as_float(u) + __int_as_float(v);
}

// ------- transpose + f32->bf16 convert of both weight matrices (1024x1024) ----
__global__ void transcvt2(const float* __restrict__ W0, bf16* __restrict__ T0,
                          const float* __restrict__ W1, bf16* __restrict__ T1) {
  const float* src = blockIdx.z ? W1 : W0;
  bf16* dst = blockIdx.z ? T1 : T0;
  __shared__ float t[32][33];
  const int bx = blockIdx.x * 32, by = blockIdx.y * 32;
  const int tx = threadIdx.x, ty = threadIdx.y;
#pragma unroll
  for (int i = 0; i < 4; ++i)
    t[ty + i * 8][tx] = src[(long)(by + ty + i * 8) * 1024 + bx + tx];
  __syncthreads();
#pragma unroll
  for (int i = 0; i < 4; ++i)
    dst[(long)(bx + ty + i * 8) * 1024 + by + tx] = (bf16)t[tx][ty + i * 8];
}

// ------- x f32 -> bf16 bulk convert ------------------------------------------
__global__ __launch_bounds__(256) void cvtx(const float* __restrict__ x,
                                            bf16* __restrict__ xb) {
  const long i = ((long)blockIdx.x * 256 + threadIdx.x) * 8;
  f32x4 u0 = *(const f32x4*)&x[i];
  f32x4 u1 = *(const f32x4*)&x[i + 4];
  bf16x8 v;
#pragma unroll
  for (int e = 0; e < 4; ++e) {
    v[e] = (bf16)u0[e];
    v[4 + e] = (bf16)u1[e];
  }
  *(bf16x8*)&xb[i] = v;
}

// ------- GEMM: C[M,1024] = A[M,1024] @ Bt[1024,1024]^T + bias -----------------
// BK=64, 128x128 tile, 4 waves. LDS swizzled (T2, rule #21):
// linear gload_lds dest; source chunk ^(row&7); read chunk ^(row&7).
template <bool OUT_F32>
__global__ __launch_bounds__(256) void gemm_bt(const bf16* __restrict__ A,
                                               const bf16* __restrict__ Bt,
                                               const float* __restrict__ bias,
                                               void* __restrict__ Cv) {
  __shared__ __align__(16) bf16 As[128 * 64];
  __shared__ __align__(16) bf16 Bs[128 * 64];
  const int tid = threadIdx.x;
  const int l = tid & 63, w = tid >> 6;
  const int wr = w >> 1, wc = w & 1;
  const int lo = l & 15, g = l >> 4;
  const int m0 = blockIdx.x * 128;
  const int n0 = blockIdx.y * 128;
  const int srow = tid >> 3;        // 0..31
  const int sc = tid & 7;           // chunk 0..7 (8 elems each)
  f32x4 acc[4][4] = {};
  for (int k0 = 0; k0 < 1024; k0 += 64) {
    __syncthreads();
#pragma unroll
    for (int h = 0; h < 4; ++h) {
      const int r = srow + h * 32;
      const int swc = (sc ^ (r & 7)) * 8;  // pre-swizzled source chunk
      gload_lds16(A + (long)(m0 + r) * 1024 + k0 + swc, As + h * 2048 + tid * 8);
      gload_lds16(Bt + (long)(n0 + r) * 1024 + k0 + swc, Bs + h * 2048 + tid * 8);
    }
    __syncthreads();
    bf16x8 af[2][4], bfr[2][4];
#pragma unroll
    for (int kk = 0; kk < 2; ++kk) {
#pragma unroll
      for (int m = 0; m < 4; ++m) {
        const int R = wr * 64 + m * 16 + lo;
        af[kk][m] = *(const bf16x8*)&As[R * 64 + (((kk * 4 + g) ^ (R & 7)) * 8)];
      }
#pragma unroll
      for (int n = 0; n < 4; ++n) {
        const int R = wc * 64 + n * 16 + lo;
        bfr[kk][n] = *(const bf16x8*)&Bs[R * 64 + (((kk * 4 + g) ^ (R & 7)) * 8)];
      }
    }
#pragma unroll
    for (int kk = 0; kk < 2; ++kk)
#pragma unroll
      for (int m = 0; m < 4; ++m)
#pragma unroll
        for (int n = 0; n < 4; ++n)
          acc[m][n] = MFMA_BF16(af[kk][m], bfr[kk][n], acc[m][n]);
  }
#pragma unroll
  for (int n = 0; n < 4; ++n) {
    const int col = n0 + wc * 64 + n * 16 + lo;
    const float bv = bias[col];
#pragma unroll
    for (int m = 0; m < 4; ++m) {
      const long row0 = m0 + wr * 64 + m * 16 + g * 4;
#pragma unroll
      for (int j = 0; j < 4; ++j) {
        if constexpr (OUT_F32)
          ((float*)Cv)[(row0 + j) * 1024 + col] = acc[m][n][j] + bv;
        else
          ((bf16*)Cv)[(row0 + j) * 1024 + col] = (bf16)(acc[m][n][j] + bv);
      }
    }
  }
}

// ---------------- flash attention, 32x32 MFMA, register softmax ---------------
// S^T = mfma32(K,Q): col=l&31=q (stats lane-local), rows=kv.
// This round: setprio around MFMA clusters (T5), defer-max THR=8 (T13),
// QK chain split 4->2x2, tree reductions.
__global__ __launch_bounds__(256) void attn(const bf16* __restrict__ proj,
                                            bf16* __restrict__ merged) {
  __shared__ __align__(16) bf16 Vt[2][64][34];  // [buf][d][kv], 17-dw row stride
  const int bid = blockIdx.x;
  const int qb = bid & 15;
  const int hh = (bid >> 4) & 15;
  const int b = bid >> 8;
  const bf16* P = proj + (long)b * 2097152 + (long)hh * 131072;  // [2048][64]
  const int tid = threadIdx.x;
  const int w = tid >> 6, l = tid & 63;
  const int l31 = l & 31;
  const int hf = l >> 5;
  const int qrow = qb * 128 + w * 32;

  const int kvp = tid >> 4;
  const int dc = tid & 15;
  int* VtI = (int*)Vt;  // [2][64][17]

  // permlane direction probe (one-time)
  int pu = l, pv;
  asm volatile("v_mov_b32 %0, %1" : "=v"(pv) : "v"(pu));
  plswap(pu, pv);
  const bool dir1 = (__shfl(pu, 33, 64) == 1);

  const float QSCALE = 0.125f * 1.44269504088896f;
  bf16x8 qf[4];
#pragma unroll
  for (int s = 0; s < 4; ++s) {
    bf16x8 t = *(const bf16x8*)&P[(long)(qrow + l31) * 64 + s * 16 + hf * 8];
#pragma unroll
    for (int e = 0; e < 8; ++e) t[e] = (bf16)((float)t[e] * QSCALE);
    qf[s] = t;
  }

  f32x16 o0 = {}, o1 = {};
  float mq = -1e30f, lq = 0.f;

  bf16x8 kA[4], kB[4];
  {
    u16x4 v0 = *(const u16x4*)&P[(long)(2 * kvp) * 64 + dc * 4];
    u16x4 v1 = *(const u16x4*)&P[(long)(2 * kvp + 1) * 64 + dc * 4];
#pragma unroll
    for (int dd = 0; dd < 4; ++dd)
      VtI[(dc * 4 + dd) * 17 + kvp] = ((int)v0[dd]) | (((int)v1[dd]) << 16);
  }
#pragma unroll
  for (int s = 0; s < 4; ++s)
    kA[s] = *(const bf16x8*)&P[(long)l31 * 64 + s * 16 + hf * 8];
  __syncthreads();

  for (int t2 = 0; t2 < 32; ++t2) {
#pragma unroll
    for (int ph = 0; ph < 2; ++ph) {
      const int t = t2 * 2 + ph;
      const int tn = (t < 63) ? t + 1 : 63;
      // 1) issue V(t+1) loads early
      u16x4 vn0 = *(const u16x4*)&P[((long)tn * 32 + 2 * kvp) * 64 + dc * 4];
      u16x4 vn1 = *(const u16x4*)&P[((long)tn * 32 + 2 * kvp + 1) * 64 + dc * 4];
      // 2) S^T = K Q^T, two independent 2-chains
      f32x16 sa, sb;
      __builtin_amdgcn_s_setprio(1);
      if (ph == 0) {
        sa = MFMA32(kA[0], qf[0], f32x16{});
        sb = MFMA32(kA[1], qf[1], f32x16{});
        sa = MFMA32(kA[2], qf[2], sa);
        sb = MFMA32(kA[3], qf[3], sb);
      } else {
        sa = MFMA32(kB[0], qf[0], f32x16{});
        sb = MFMA32(kB[1], qf[1], f32x16{});
        sa = MFMA32(kB[2], qf[2], sa);
        sb = MFMA32(kB[3], qf[3], sb);
      }
      __builtin_amdgcn_s_setprio(0);
      // 3) prefetch K(t+1)
#pragma unroll
      for (int sx = 0; sx < 4; ++sx) {
        bf16x8 kv8 = *(const bf16x8*)&P[((long)tn * 32 + l31) * 64 + sx * 16 + hf * 8];
        if (ph == 0) kB[sx] = kv8; else kA[sx] = kv8;
      }
      f32x16 s;
#pragma unroll
      for (int i = 0; i < 16; ++i) s[i] = sa[i] + sb[i];
      // 4) online softmax, tree max + defer-max (THR=8)
      float q0 = fmaxf(fmaxf(s[0], s[1]), fmaxf(s[2], s[3]));
      float q1 = fmaxf(fmaxf(s[4], s[5]), fmaxf(s[6], s[7]));
      float q2 = fmaxf(fmaxf(s[8], s[9]), fmaxf(s[10], s[11]));
      float q3 = fmaxf(fmaxf(s[12], s[13]), fmaxf(s[14], s[15]));
      float mx = fmaxf(fmaxf(q0, q1), fmaxf(q2, q3));
      mx = swap_max(mx);
      if (!__all(mx <= mq + 8.f)) {
        const float mnew = fmaxf(mq, mx);
        const float corr = EXP2F(mq - mnew);
        mq = mnew;
        lq *= corr;
#pragma unroll
        for (int i = 0; i < 16; ++i) { o0[i] *= corr; o1[i] *= corr; }
      }
#pragma unroll
      for (int i = 0; i < 16; ++i) s[i] = EXP2F(s[i] - mq);
      // tree sum
      {
        float a0 = s[0] + s[1], a1 = s[2] + s[3], a2 = s[4] + s[5], a3 = s[6] + s[7];
        float a4 = s[8] + s[9], a5 = s[10] + s[11], a6 = s[12] + s[13], a7 = s[14] + s[15];
        float b0 = a0 + a1, b1 = a2 + a3, b2 = a4 + a5, b3 = a6 + a7;
        float ps = (b0 + b1) + (b2 + b3);
        ps = swap_add(ps);
        lq += ps;
      }
      // 5) pack P -> PV B-fragments
      int p0 = cvtpk(s[0], s[1]), p1 = cvtpk(s[2], s[3]);
      int p2 = cvtpk(s[4], s[5]), p3 = cvtpk(s[6], s[7]);
      int p4 = cvtpk(s[8], s[9]), p5 = cvtpk(s[10], s[11]);
      int p6 = cvtpk(s[12], s[13]), p7 = cvtpk(s[14], s[15]);
      if (dir1) {
        plswap(p0, p2); plswap(p1, p3); plswap(p4, p6); plswap(p5, p7);
      } else {
        plswap(p2, p0); plswap(p3, p1); plswap(p6, p4); plswap(p7, p5);
      }
      int bi0[4] = {p0, p1, p2, p3};
      int bi1[4] = {p4, p5, p6, p7};
      bf16x8 pb0 = *(bf16x8*)bi0;
      bf16x8 pb1 = *(bf16x8*)bi1;
      // 6) O^T += V^T P^T
      {
        bf16x8 va0 = *(const bf16x8*)&Vt[ph][l31][hf * 8];
        bf16x8 va1 = *(const bf16x8*)&Vt[ph][l31][16 + hf * 8];
        bf16x8 va2 = *(const bf16x8*)&Vt[ph][32 + l31][hf * 8];
        bf16x8 va3 = *(const bf16x8*)&Vt[ph][32 + l31][16 + hf * 8];
        __builtin_amdgcn_s_setprio(1);
        o0 = MFMA32(va0, pb0, o0);
        o1 = MFMA32(va2, pb0, o1);
        o0 = MFMA32(va1, pb1, o0);
        o1 = MFMA32(va3, pb1, o1);
        __builtin_amdgcn_s_setprio(0);
      }
      // 7) write V(t+1) into the other buffer, then barrier
      {
        int* W = VtI + (ph ^ 1) * (64 * 17);
#pragma unroll
        for (int dd = 0; dd < 4; ++dd)
          W[(dc * 4 + dd) * 17 + kvp] = ((int)vn0[dd]) | (((int)vn1[dd]) << 16);
      }
      __syncthreads();
    }
  }

  // epilogue
  const float inv = 1.0f / lq;
  bf16* mb = merged + (long)b * 2097152 + hh * 64;
  const long rowoff = (long)(qrow + l31) * 1024;
  const int dbase[8] = {0, 2, 8, 10, 16, 18, 24, 26};
#pragma unroll
  for (int r = 0; r < 8; ++r) {
    const int d = dbase[r] + 4 * hf;
    *(int*)&mb[rowoff + d] = cvtpk(o0[2 * r] * inv, o0[2 * r + 1] * inv);
    *(int*)&mb[rowoff + 32 + d] = cvtpk(o1[2 * r] * inv, o1[2 * r + 1] * inv);
  }
}

extern "C" void kernel_launch(void* const* d_in, const int* in_sizes, int n_in,
                              void* d_out, int out_size, void* d_ws, size_t ws_size,
                              hipStream_t stream) {
  const float* x = (const float*)d_in[0];
  const float* Wqkv = (const float*)d_in[1];
  const float* bqkv = (const float*)d_in[2];
  const float* Wo = (const float*)d_in[3];
  const float* bo = (const float*)d_in[4];
  float* out = (float*)d_out;

  char* ws = (char*)d_ws;
  bf16* proj = (bf16*)(ws);                     // 16.78 MB  [4][2048][1024]
  bf16* merged = (bf16*)(ws + 16777216);        // 16.78 MB  (aliases xb)
  bf16* xb = (bf16*)(ws + 16777216);            // x as bf16 (dead after gemm1)
  bf16* WqkvT = (bf16*)(ws + 33554432);         // 2 MB      [n][k]
  bf16* WoT = (bf16*)(ws + 35651584);           // 2 MB      [n][k]

  transcvt2<<<dim3(32, 32, 2), dim3(32, 8), 0, stream>>>(Wqkv, WqkvT, Wo, WoT);
  cvtx<<<dim3(4096), dim3(256), 0, stream>>>(x, xb);
  gemm_bt<false><<<dim3(64, 8), dim3(256), 0, stream>>>(xb, WqkvT, bqkv, proj);
  attn<<<dim3(1024), dim3(256), 0, stream>>>(proj, merged);
  gemm_bt<true><<<dim3(64, 8), dim3(256), 0, stream>>>(merged, WoT, bo, out);
}